// Round 27
// baseline (1000.805 us; speedup 1.0000x reference)
//
#include <hip/hip_runtime.h>
#include <hip/hip_bf16.h>
#include <math.h>

// ---------------- problem constants ----------------
#define BDIM 32
#define HDIM 56
#define WDIM 56
#define CDIM 384
#define NHEAD 12
#define WSZ 14
#define SSZ 7
#define LDIM (HDIM*WDIM)        // 3136
#define NTOK (WSZ*WSZ)          // 196
#define HDHEAD (CDIM/NHEAD)     // 32
#define HIDDIM (4*CDIM)         // 1536
#define NWIN 16
#define BWIN (BDIM*NWIN)        // 512
#define MROWS (BDIM*LDIM)       // 100352 == BWIN*NTOK
#define EPSLN 1e-5f
#define ATTSCALE 0.17677669529663687f   // 32^-0.5
#define QKVC (3*CDIM)           // 1152, contiguous qkv row stride
#define TBLM 224                // bias table m' extent (196 real + -inf pad)
#define NQKVW (3*CDIM*CDIM)     // 442368
#define NPROJW (CDIM*CDIM)      // 147456
#define NFCW  (HIDDIM*CDIM)     // 589824
#define TBLN  (NHEAD*NTOK*TBLM) // 526848

// padded LDS strides (shorts) for attention
#define KROW 40
#define VROW 232

typedef __hip_bfloat16 bf16;
typedef __attribute__((ext_vector_type(8))) short bf16x8;   // 8 bf16 = 4 VGPRs
typedef __attribute__((ext_vector_type(4))) short s16x4;    // 4 bf16 = 1 b64
typedef __attribute__((ext_vector_type(2))) short s16x2;
typedef __attribute__((ext_vector_type(4))) float f32x4;
typedef __attribute__((ext_vector_type(4))) unsigned int u32x4;

// v_mfma_f32_16x16x16_bf16 (gfx950; A/B = 2 VGPRs = 4 bf16). Clang builtin is
// the gfx90a-era "...16x16x16bf16_1k" name. Host pass can't see target
// builtins — gate on device compile; host stub only parses, never executes.
#if defined(__HIP_DEVICE_COMPILE__)
#define MFMA16(a,b,c) __builtin_amdgcn_mfma_f32_16x16x16bf16_1k(a,b,c,0,0,0)
#else
#define MFMA16(a,b,c) (c)
#endif

// async global->LDS, 16B per lane, wave-uniform LDS base
#define ASYNC16(gp, lp) __builtin_amdgcn_global_load_lds( \
    (__attribute__((address_space(1))) void*)(gp),        \
    (__attribute__((address_space(3))) void*)(lp), 16, 0, 0)

// float -> bf16 bit pattern as short (type-consistent with short LDS arrays)
static __device__ __forceinline__ short f2bfs(float x) {
  union { bf16 h; short s; } u; u.h = __float2bfloat16(x); return u.s;
}
static __device__ __forceinline__ float bfs2f(short s) {
  unsigned int u = ((unsigned int)(unsigned short)s) << 16;
  float f; __builtin_memcpy(&f, &u, 4); return f;
}

// ---------------- merged prologue: qkv/proj weight cvt + bias table ----------------
__global__ __launch_bounds__(256) void k_prep(const float* __restrict__ qkv_w,
    const float* __restrict__ proj_w, const float* __restrict__ rt,
    bf16* __restrict__ wq, bf16* __restrict__ wp, unsigned int* __restrict__ tbl)
{
  int i = blockIdx.x*256 + threadIdx.x;
  if (i < NQKVW) {
    wq[i] = __float2bfloat16(qkv_w[i]);
  } else if (i < NQKVW + NPROJW) {
    int j = i - NQKVW;
    wp[j] = __float2bfloat16(proj_w[j]);
  } else if (i < NQKVW + NPROJW + TBLN) {
    int idx = i - (NQKVW + NPROJW);
    int mp   = idx % TBLM;
    int rest = idx / TBLM;
    int n    = rest % NTOK;
    int head = rest / NTOK;
    unsigned int outv;
    if (mp >= NTOK) {
      outv = 0x0000FF80u;                        // lo = bf16 -inf, hi = 0
    } else {
      int ni = n / WSZ,  nj = n % WSZ;
      int mi = mp / WSZ, mj = mp % WSZ;
      int ridx = (ni - mi + 13)*27 + (nj - mj + 13);
      unsigned int lo = (unsigned short)f2bfs(rt[ridx*2*NHEAD + head]);
      unsigned int hi = (unsigned short)f2bfs(rt[ridx*2*NHEAD + NHEAD + head]);
      outv = lo | (hi << 16);
    }
    tbl[idx] = outv;
  }
}

// ---------------- merged fc weight convert (fc1 + fc2) ----------------
__global__ __launch_bounds__(256) void k_cvt2(const float* __restrict__ fc1_w,
    const float* __restrict__ fc2_w, bf16* __restrict__ wf1, bf16* __restrict__ wf2)
{
  int i = blockIdx.x*256 + threadIdx.x;
  if (i < NFCW) wf1[i] = __float2bfloat16(fc1_w[i]);
  else          wf2[i - NFCW] = __float2bfloat16(fc2_w[i - NFCW]);
}

// ---------------- LN: wave-per-row, vectorized, no LDS/barrier ----------------
template<bool WIN, typename TIN>
__global__ __launch_bounds__(256) void k_ln(const TIN* __restrict__ xin,
    const float* __restrict__ gw, const float* __restrict__ gb,
    bf16* __restrict__ out)
{
  int lane = threadIdx.x & 63, wid = threadIdx.x >> 6;
  int r = blockIdx.x*4 + wid;
  const TIN* xp = xin + (size_t)r * CDIM;
  float v[6];
  if constexpr (sizeof(TIN) == 4) {
    float4 a = *(const float4*)((const float*)xp + lane*4);
    float2 b = *(const float2*)((const float*)xp + 256 + lane*2);
    v[0]=a.x; v[1]=a.y; v[2]=a.z; v[3]=a.w; v[4]=b.x; v[5]=b.y;
  } else {
    s16x4 a = *(const s16x4*)((const short*)xp + lane*4);
    s16x2 b = *(const s16x2*)((const short*)xp + 256 + lane*2);
    v[0]=bfs2f(a[0]); v[1]=bfs2f(a[1]); v[2]=bfs2f(a[2]); v[3]=bfs2f(a[3]);
    v[4]=bfs2f(b[0]); v[5]=bfs2f(b[1]);
  }
  float s = 0.f, ss = 0.f;
  #pragma unroll
  for (int j = 0; j < 6; j++) { s += v[j]; ss += v[j]*v[j]; }
  #pragma unroll
  for (int o = 1; o < 64; o <<= 1) { s += __shfl_xor(s, o); ss += __shfl_xor(ss, o); }
  float mean = s * (1.0f/CDIM);
  float var  = ss * (1.0f/CDIM) - mean*mean;
  float rstd = rsqrtf(var + EPSLN);

  size_t orow;
  if (WIN) {
    int b = r / LDIM, l = r % LDIM;
    int h = l / WDIM, w = l % WDIM;
    int h2 = (h + HDIM - SSZ) % HDIM, w2 = (w + WDIM - SSZ) % WDIM;
    int wh = h2 / WSZ, ii = h2 % WSZ, ww = w2 / WSZ, jj = w2 % WSZ;
    int b_ = b*NWIN + wh*4 + ww;
    int n  = ii*WSZ + jj;
    orow = ((size_t)b_*NTOK + n) * CDIM;
  } else {
    orow = (size_t)r * CDIM;
  }
  float4 w4 = *(const float4*)(gw + lane*4);
  float2 w2 = *(const float2*)(gw + 256 + lane*2);
  float4 g4 = *(const float4*)(gb + lane*4);
  float2 g2 = *(const float2*)(gb + 256 + lane*2);
  s16x4 o4;
  o4[0] = f2bfs((v[0]-mean)*rstd*w4.x + g4.x);
  o4[1] = f2bfs((v[1]-mean)*rstd*w4.y + g4.y);
  o4[2] = f2bfs((v[2]-mean)*rstd*w4.z + g4.z);
  o4[3] = f2bfs((v[3]-mean)*rstd*w4.w + g4.w);
  *(s16x4*)((short*)out + orow + lane*4) = o4;
  s16x2 o2;
  o2[0] = f2bfs((v[4]-mean)*rstd*w2.x + g2.x);
  o2[1] = f2bfs((v[5]-mean)*rstd*w2.y + g2.y);
  *(s16x2*)((short*)out + orow + 256 + lane*2) = o2;
}

// ---------------- MFMA GEMM: C = A(bf16,MxK) @ Wb(bf16,NCxK)^T ----------------
// 256x128 tile, 512 threads (8 waves = 4M x 2N), BK=32, TRIPLE-buffered 72 KB
// LDS, single-barrier 2-tile-deep pipeline. FROZEN (best of 10 variants).
template<int KD, int EPI>
__global__ __launch_bounds__(512, 4) void k_mgemm(
    const bf16* __restrict__ A, const bf16* __restrict__ Wb,
    const float* __restrict__ bias, const float* __restrict__ aux,
    const bf16* __restrict__ auxb,
    float* __restrict__ outf, bf16* __restrict__ outb, int gx)
{
  __shared__ short As[3][256*32];   // 16 KB each
  __shared__ short Bs[3][128*32];   // 8 KB each  (total 72 KB)
  int tid  = threadIdx.x;
  int lane = tid & 63, wid = tid >> 6;
  int c15 = lane & 15, h4 = lane >> 4;
  int wr = wid >> 1, wc = wid & 1;          // 4 M-quarters x 2 N-halves

  int nwg = gridDim.x, bid = blockIdx.x;
  int swz = (bid & 7) * (nwg >> 3) + (bid >> 3);
  int ty = swz / gx, tx = swz - ty * gx;
  int row0 = ty * 256, col0 = tx * 128;

  f32x4 acc[4][4] = {};          // [n][m]

  int r0  = tid >> 2, b0 = tid & 3;
  int sk0 = (b0 ^ (r0 & 3) ^ ((r0 >> 2) & 3)) * 8;

  const int NT = KD / 32;

#define STAGE_T(k0, bf) do { \
    ASYNC16(A  + (size_t)(row0 + r0)*KD       + (k0) + sk0, &As[bf][tid*8]); \
    ASYNC16(A  + (size_t)(row0 + r0 + 128)*KD + (k0) + sk0, &As[bf][(tid+512)*8]); \
    ASYNC16(Wb + (size_t)(col0 + r0)*KD       + (k0) + sk0, &Bs[bf][tid*8]); \
  } while (0)

  STAGE_T(0, 0);                      // prologue: tiles 0,1 in flight
  STAGE_T(32, 1);

  int rblk = (h4 ^ (c15 & 3) ^ ((c15 >> 2) & 3)) * 8;   // swizzled read offset

  for (int t = 0; t < NT; t++) {
    int cur = t % 3;
    if (t + 1 < NT) {
      asm volatile("s_waitcnt vmcnt(3)" ::: "memory");   // own tile-t loads done
    } else {
      asm volatile("s_waitcnt vmcnt(0)" ::: "memory");
    }
    __builtin_amdgcn_s_barrier();     // tile t complete block-wide; buf[(t+2)%3] readers done
    __builtin_amdgcn_sched_barrier(0);

    if (t + 2 < NT) STAGE_T((t+2)*32, (t+2) % 3);

    bf16x8 af[4], bfr[4];
    #pragma unroll
    for (int m = 0; m < 4; m++)
      af[m] = *reinterpret_cast<const bf16x8*>(&As[cur][(wr*64 + m*16 + c15)*32 + rblk]);
    #pragma unroll
    for (int n = 0; n < 4; n++)
      bfr[n] = *reinterpret_cast<const bf16x8*>(&Bs[cur][(wc*64 + n*16 + c15)*32 + rblk]);
    __builtin_amdgcn_s_setprio(1);
    #pragma unroll
    for (int n = 0; n < 4; n++)
      #pragma unroll
      for (int m = 0; m < 4; m++)
        acc[n][m] = __builtin_amdgcn_mfma_f32_16x16x32_bf16(bfr[n], af[m], acc[n][m], 0, 0, 0);
    __builtin_amdgcn_s_setprio(0);
    __builtin_amdgcn_sched_barrier(0);
  }
#undef STAGE_T

  int rb = row0 + wr*64 + c15;
  int cb = col0 + wc*64 + h4*4;
  #pragma unroll
  for (int m = 0; m < 4; m++) {
    int r = rb + m*16;
    if constexpr (EPI == 0) {
      #pragma unroll
      for (int n = 0; n < 4; n++) {
        int c0 = cb + n*16;
        f32x4 v = acc[n][m];
        f32x4 b4 = *(const f32x4*)&bias[c0];
        float scl = (c0 < CDIM) ? ATTSCALE : 1.f;
        s16x4 o;
        #pragma unroll
        for (int i = 0; i < 4; i++) o[i] = f2bfs((v[i] + b4[i]) * scl);
        *(s16x4*)&outb[(size_t)r*QKVC + c0] = o;
      }
    } else if constexpr (EPI == 1) {
      int b_ = r / NTOK, nn = r % NTOK;
      int b = b_ >> 4, wi = b_ & 15, wh = wi >> 2, ww = wi & 3;
      int ii = nn / WSZ, jj = nn % WSZ;
      int hh = (wh*WSZ + ii + SSZ) % HDIM;
      int wcc = (ww*WSZ + jj + SSZ) % WDIM;
      size_t rr = ((size_t)b*LDIM + hh*WDIM + wcc) * CDIM;
      #pragma unroll
      for (int n = 0; n < 4; n++) {
        int c0 = cb + n*16;
        f32x4 v = acc[n][m];
        f32x4 b4 = *(const f32x4*)&bias[c0];
        f32x4 a4 = *(const f32x4*)&aux[rr + c0];
        s16x4 o;
        #pragma unroll
        for (int i = 0; i < 4; i++) o[i] = f2bfs(a4[i] + v[i] + b4[i]);
        *(s16x4*)&outb[rr + c0] = o;
      }
    } else {
      #pragma unroll
      for (int n = 0; n < 4; n++) {
        int c0 = cb + n*16;
        f32x4 v = acc[n][m];
        f32x4 b4 = *(const f32x4*)&bias[c0];
        s16x4 ab = *(const s16x4*)&auxb[(size_t)r*CDIM + c0];
        f32x4 o;
        #pragma unroll
        for (int i = 0; i < 4; i++) o[i] = v[i] + b4[i] + bfs2f(ab[i]);
        *(f32x4*)&outf[(size_t)r*CDIM + c0] = o;
      }
    }
  }
}

// ---------------- WIDE-N MFMA GEMM for fc1: 256x256 tile, K=384, GELU ----------------
// 512 threads (8 waves = 2M x 4N, per-wave 128x64), BK=32, TRIPLE-buffered
// 96 KB LDS, single-barrier depth-2 counted-vmcnt pipeline (round-21 schedule
// scaled). Per-iter 32 MFMA : 4 loads (vs 16:3) — better latency amortization.
__global__ __launch_bounds__(512, 1) void k_mgemm_w(
    const bf16* __restrict__ A, const bf16* __restrict__ Wb,
    const float* __restrict__ bias, bf16* __restrict__ outb, int gx)
{
  __shared__ short As[3][256*32];   // 16 KB each
  __shared__ short Bs[3][256*32];   // 16 KB each  (total 96 KB)
  int tid  = threadIdx.x;
  int lane = tid & 63, wid = tid >> 6;
  int c15 = lane & 15, h4 = lane >> 4;
  int wr = wid >> 2, wc = wid & 3;          // 2 M-halves x 4 N-quarters

  int nwg = gridDim.x, bid = blockIdx.x;
  int swz = (bid & 7) * (nwg >> 3) + (bid >> 3);
  int ty = swz / gx, tx = swz - ty * gx;
  int row0 = ty * 256, col0 = tx * 256;

  f32x4 acc[4][8] = {};          // [n][m]

  int r0  = tid >> 2, b0 = tid & 3;
  int sk0 = (b0 ^ (r0 & 3) ^ ((r0 >> 2) & 3)) * 8;

  const int KD = CDIM, NT = KD / 32;   // 12

#define STAGE_W(k0, bf) do { \
    ASYNC16(A  + (size_t)(row0 + r0)*KD       + (k0) + sk0, &As[bf][tid*8]); \
    ASYNC16(A  + (size_t)(row0 + r0 + 128)*KD + (k0) + sk0, &As[bf][(tid+512)*8]); \
    ASYNC16(Wb + (size_t)(col0 + r0)*KD       + (k0) + sk0, &Bs[bf][tid*8]); \
    ASYNC16(Wb + (size_t)(col0 + r0 + 128)*KD + (k0) + sk0, &Bs[bf][(tid+512)*8]); \
  } while (0)

  STAGE_W(0, 0);                      // prologue: tiles 0,1 in flight
  STAGE_W(32, 1);

  int rblk = (h4 ^ (c15 & 3) ^ ((c15 >> 2) & 3)) * 8;   // swizzled read offset

  for (int t = 0; t < NT; t++) {
    int cur = t % 3;
    if (t + 1 < NT) {
      asm volatile("s_waitcnt vmcnt(4)" ::: "memory");   // own tile-t loads done
    } else {
      asm volatile("s_waitcnt vmcnt(0)" ::: "memory");
    }
    __builtin_amdgcn_s_barrier();     // tile t complete; buf[(t+2)%3] readers done
    __builtin_amdgcn_sched_barrier(0);

    if (t + 2 < NT) STAGE_W((t+2)*32, (t+2) % 3);

    bf16x8 af[8], bfr[4];
    #pragma unroll
    for (int m = 0; m < 8; m++)
      af[m] = *reinterpret_cast<const bf16x8*>(&As[cur][(wr*128 + m*16 + c15)*32 + rblk]);
    #pragma unroll
    for (int n = 0; n < 4; n++)
      bfr[n] = *reinterpret_cast<const bf16x8*>(&Bs[cur][(wc*64 + n*16 + c15)*32 + rblk]);
    __builtin_amdgcn_s_setprio(1);
    #pragma unroll
    for (int n = 0; n < 4; n++)
      #pragma unroll
      for (int m = 0; m < 8; m++)
        acc[n][m] = __builtin_amdgcn_mfma_f32_16x16x32_bf16(bfr[n], af[m], acc[n][m], 0, 0, 0);
    __builtin_amdgcn_s_setprio(0);
    __builtin_amdgcn_sched_barrier(0);
  }
#undef STAGE_W

  // epilogue: fc1 + exact GELU -> bf16 (row-major [r][HIDDIM])
  int rb = row0 + wr*128 + c15;
  int cb = col0 + wc*64 + h4*4;
  #pragma unroll
  for (int m = 0; m < 8; m++) {
    int r = rb + m*16;
    #pragma unroll
    for (int n = 0; n < 4; n++) {
      int c0 = cb + n*16;
      f32x4 v = acc[n][m];
      f32x4 b4 = *(const f32x4*)&bias[c0];
      s16x4 o;
      #pragma unroll
      for (int i = 0; i < 4; i++) {
        float val = v[i] + b4[i];
        val = 0.5f * val * (1.0f + erff(val * 0.70710678118654752f));
        o[i] = f2bfs(val);
      }
      *(s16x4*)&outb[(size_t)r*HIDDIM + c0] = o;
    }
  }
}

// ---------------- MFMA fused window attention (register-resident P) ----------------
// Swapped QK^T; softmax fused into t-loop; unnormalized bf16 pf[13] feeds
// 16x16x16 PV MFMA. Per-HEAD bias/rscale table; edge-window specialization.
// launch_bounds (256,2) — proven best.
__global__ __launch_bounds__(256, 2) void k_attn_mfma(const bf16* __restrict__ qkv,
    const unsigned int* __restrict__ tbl, bf16* __restrict__ out)
{
  __shared__ short  Ks[208*KROW];   // [m][k], rows 196..207 zero, padded stride
  __shared__ short  Vt[32*VROW];    // [d][m], cols 196..223 zero, padded stride

  int blk = blockIdx.x;
  int b_ = blk / NHEAD, head = blk % NHEAD;
  int tid = threadIdx.x, lane = tid & 63, wid = tid >> 6;
  int c15 = lane & 15, h4 = lane >> 4;

  // ---- staging ----
  const bf16* rowbase = qkv + (size_t)b_*NTOK*QKVC + head*HDHEAD;
  const bf16* kp = rowbase + CDIM;      // k block
  const bf16* vp = rowbase + 2*CDIM;    // v block
  for (int c = tid; c < 784; c += 256) {          // 196 rows x 4 chunks of 8
    int m = c >> 2, k8 = (c & 3) * 8;
    *(bf16x8*)&Ks[m*KROW + k8] = *(const bf16x8*)(kp + (size_t)m*QKVC + k8);
    bf16x8 vv = *(const bf16x8*)(vp + (size_t)m*QKVC + k8);
    #pragma unroll
    for (int j = 0; j < 8; j++) Vt[(k8+j)*VROW + m] = vv[j];
  }
  for (int e = tid; e < 12*KROW; e += 256) Ks[196*KROW + e] = 0;
  for (int e = tid; e < 32*28; e += 256) Vt[(e/28)*VROW + 196 + (e%28)] = 0;
  __syncthreads();

  int wi = b_ & 15, wh = wi >> 2, ww = wi & 3;
  int whb = wh*WSZ, wwb = ww*WSZ;
  bool edgewin = (wh == 3) || (ww == 3);   // block-uniform: mask can be nonzero

  const unsigned int* thead = tbl + (size_t)head*NTOK*TBLM;

  bf16* op = out + (size_t)b_*NTOK*CDIM + head*HDHEAD;

  for (int s = wid; s < 13; s += 4) {             // wave-independent strips
    int n = s*16 + c15;
    int ncl = min(n, NTOK-1);
    bf16x8 qf = *(const bf16x8*)(rowbase + (size_t)ncl*QKVC + h4*8);
    const unsigned int* trow = thead + (size_t)ncl*TBLM;

    float sum = 0.f;
    s16x4 pf[13];                                  // unnormalized bf16 P

    if (edgewin) {
      int ni = ncl / 14, nj = ncl - (ncl/14)*14;
      int nreg = ((whb + ni) < 42 ? 0 : ((whb + ni) < 49 ? 1 : 2))*3
               + ((wwb + nj) < 42 ? 0 : ((wwb + nj) < 49 ? 1 : 2));
      #pragma unroll
      for (int t = 0; t < 13; t++) {
        bf16x8 kf = *(const bf16x8*)&Ks[(t*16 + c15)*KROW + h4*8];
        f32x4 sct = __builtin_amdgcn_mfma_f32_16x16x32_bf16(kf, qf, (f32x4){0.f,0.f,0.f,0.f}, 0, 0, 0);

        int m0 = t*16 + h4*4;
        u32x4 tv = *(const u32x4*)&trow[m0];       // 16B aligned, linear m'
        int mi = m0 / 14, mj = m0 - (m0/14)*14;
        #pragma unroll
        for (int i = 0; i < 4; i++) {
          int ha = whb + mi, wa = wwb + mj;
          int mr = (ha < 42 ? 0 : (ha < 49 ? 1 : 2))*3
                 + (wa < 42 ? 0 : (wa < 49 ? 1 : 2));
          float sv = sct[i] + bfs2f((short)(tv[i] & 0xFFFFu));
          if (mr != nreg) sv -= 100.f;
          float e = __expf(sv);                    // no-max softmax; -inf -> 0
          sum += e;
          pf[t][i] = f2bfs(e * bfs2f((short)(tv[i] >> 16)));   // fold rscale
          mj++; bool w = (mj == 14); mj = w ? 0 : mj; mi += w ? 1 : 0;
        }
      }
    } else {
      // interior window: mask == 0 everywhere; no region math needed
      #pragma unroll
      for (int t = 0; t < 13; t++) {
        bf16x8 kf = *(const bf16x8*)&Ks[(t*16 + c15)*KROW + h4*8];
        f32x4 sct = __builtin_amdgcn_mfma_f32_16x16x32_bf16(kf, qf, (f32x4){0.f,0.f,0.f,0.f}, 0, 0, 0);

        u32x4 tv = *(const u32x4*)&trow[t*16 + h4*4];
        #pragma unroll
        for (int i = 0; i < 4; i++) {
          float e = __expf(sct[i] + bfs2f((short)(tv[i] & 0xFFFFu)));
          sum += e;
          pf[t][i] = f2bfs(e * bfs2f((short)(tv[i] >> 16)));   // fold rscale
        }
      }
    }

    sum += __shfl_xor(sum, 16);
    sum += __shfl_xor(sum, 32);
    float inv = 1.f / sum;

    // PV: O^T[d][n] via 16x16x16 MFMA, A = Vt rows (d), B = pf (unnormalized)
    f32x4 o0 = {0.f,0.f,0.f,0.f}, o1 = {0.f,0.f,0.f,0.f};
    #pragma unroll
    for (int t = 0; t < 13; t++) {
      s16x4 va = *(const s16x4*)&Vt[c15*VROW + t*16 + h4*4];
      s16x4 vb = *(const s16x4*)&Vt[(16 + c15)*VROW + t*16 + h4*4];
      o0 = MFMA16(va, pf[t], o0);
      o1 = MFMA16(vb, pf[t], o1);
    }

    if (n < NTOK) {
      s16x4 w0, w1;
      #pragma unroll
      for (int i = 0; i < 4; i++) {
        w0[i] = f2bfs(o0[i] * inv);
        w1[i] = f2bfs(o1[i] * inv);
      }
      *(s16x4*)((short*)op + (size_t)n*CDIM + h4*4)      = w0;
      *(s16x4*)((short*)op + (size_t)n*CDIM + 16 + h4*4) = w1;
    }
  }
}

// ---------------- launch ----------------
extern "C" void kernel_launch(void* const* d_in, const int* in_sizes, int n_in,
                              void* d_out, int out_size, void* d_ws, size_t ws_size,
                              hipStream_t stream)
{
  const float* x      = (const float*)d_in[0];
  const float* n1w    = (const float*)d_in[1];
  const float* n1b    = (const float*)d_in[2];
  const float* qkv_w  = (const float*)d_in[3];
  const float* qkv_b  = (const float*)d_in[4];
  const float* proj_w = (const float*)d_in[5];
  const float* proj_b = (const float*)d_in[6];
  const float* rt     = (const float*)d_in[7];
  const float* n2w    = (const float*)d_in[8];
  const float* n2b    = (const float*)d_in[9];
  const float* fc1_w  = (const float*)d_in[10];
  const float* fc1_b  = (const float*)d_in[11];
  const float* fc2_w  = (const float*)d_in[12];
  const float* fc2_b  = (const float*)d_in[13];

  char* ws = (char*)d_ws;
  const size_t SZ_BF = (size_t)MROWS * CDIM * 2;   // 77,070,336 B
  // arena (total exactly 8*SZ_BF, proven footprint):
  //  R0 [0,1SZ):    xw -> attnout -> (after proj) wf1,wf2
  //  R1 [1SZ,4SZ):  qkv (contiguous [r][1152]) -> x2(bf16,[1SZ,2SZ)) + hln([2SZ,3SZ))
  //  R2 [4SZ,8SZ):  wq,wp (at 4SZ) + tbl (at 5SZ, dead before fc1) -> hid
  bf16*  xw      = (bf16*)ws;
  bf16*  attnout = (bf16*)ws;
  bf16*  qkv     = (bf16*)(ws + SZ_BF);
  bf16*  x2b     = (bf16*)(ws + SZ_BF);
  bf16*  hln     = (bf16*)(ws + 2*SZ_BF);
  bf16*  hid     = (bf16*)(ws + 4*SZ_BF);
  bf16* wq  = (bf16*)(ws + 4*SZ_BF);  // lives in R2 until fc1 clobbers it
  bf16* wp  = wq + NQKVW;
  bf16* wf1 = (bf16*)ws;              // converted into R0 after proj GEMM
  bf16* wf2 = wf1 + NFCW;
  unsigned int* tbl = (unsigned int*)(ws + 5*SZ_BF);  // 2.1 MB, dead at fc1

  k_prep<<<(NQKVW + NPROJW + TBLN + 255)/256, 256, 0, stream>>>(
      qkv_w, proj_w, rt, wq, wp, tbl);

  k_ln<true, float><<<MROWS/4, 256, 0, stream>>>(x, n1w, n1b, xw);
  k_mgemm<CDIM, 0><<<(MROWS/256)*9, 512, 0, stream>>>(
      xw, wq, qkv_b, nullptr, nullptr, nullptr, qkv, 9);
  k_attn_mfma<<<BWIN*NHEAD, 256, 0, stream>>>(qkv, tbl, attnout);
  k_mgemm<CDIM, 1><<<(MROWS/256)*3, 512, 0, stream>>>(
      attnout, wp, proj_b, x, nullptr, nullptr, x2b, 3);

  k_cvt2<<<(2*NFCW)/256, 256, 0, stream>>>(fc1_w, fc2_w, wf1, wf2);

  k_ln<false, bf16><<<MROWS/4, 256, 0, stream>>>(x2b, n2w, n2b, hln);
  k_mgemm_w<<<(MROWS/256)*6, 512, 0, stream>>>(hln, wf1, fc1_b, hid, 6);
  k_mgemm<HIDDIM, 3><<<(MROWS/256)*3, 512, 0, stream>>>(
      hid, wf2, fc2_b, nullptr, x2b, (float*)d_out, nullptr, 3);
}

// Round 28
// 973.236 us; speedup vs baseline: 1.0283x; 1.0283x over previous
//
#include <hip/hip_runtime.h>
#include <hip/hip_bf16.h>
#include <math.h>

// ---------------- problem constants ----------------
#define BDIM 32
#define HDIM 56
#define WDIM 56
#define CDIM 384
#define NHEAD 12
#define WSZ 14
#define SSZ 7
#define LDIM (HDIM*WDIM)        // 3136
#define NTOK (WSZ*WSZ)          // 196
#define HDHEAD (CDIM/NHEAD)     // 32
#define HIDDIM (4*CDIM)         // 1536
#define NWIN 16
#define BWIN (BDIM*NWIN)        // 512
#define MROWS (BDIM*LDIM)       // 100352 == BWIN*NTOK
#define EPSLN 1e-5f
#define ATTSCALE 0.17677669529663687f   // 32^-0.5
#define QKVC (3*CDIM)           // 1152, contiguous qkv row stride
#define TBLM 224                // bias table m' extent (196 real + -inf pad)
#define NQKVW (3*CDIM*CDIM)     // 442368
#define NPROJW (CDIM*CDIM)      // 147456
#define NFCW  (HIDDIM*CDIM)     // 589824
#define TBLN  (NHEAD*NTOK*TBLM) // 526848

// padded LDS strides (shorts) for attention
#define KROW 40
#define VROW 232

typedef __hip_bfloat16 bf16;
typedef __attribute__((ext_vector_type(8))) short bf16x8;   // 8 bf16 = 4 VGPRs
typedef __attribute__((ext_vector_type(4))) short s16x4;    // 4 bf16 = 1 b64
typedef __attribute__((ext_vector_type(2))) short s16x2;
typedef __attribute__((ext_vector_type(4))) float f32x4;
typedef __attribute__((ext_vector_type(4))) unsigned int u32x4;

// v_mfma_f32_16x16x16_bf16 (gfx950; A/B = 2 VGPRs = 4 bf16). Clang builtin is
// the gfx90a-era "...16x16x16bf16_1k" name. Host pass can't see target
// builtins — gate on device compile; host stub only parses, never executes.
#if defined(__HIP_DEVICE_COMPILE__)
#define MFMA16(a,b,c) __builtin_amdgcn_mfma_f32_16x16x16bf16_1k(a,b,c,0,0,0)
#else
#define MFMA16(a,b,c) (c)
#endif

// async global->LDS, 16B per lane, wave-uniform LDS base
#define ASYNC16(gp, lp) __builtin_amdgcn_global_load_lds( \
    (__attribute__((address_space(1))) void*)(gp),        \
    (__attribute__((address_space(3))) void*)(lp), 16, 0, 0)

// float -> bf16 bit pattern as short (type-consistent with short LDS arrays)
static __device__ __forceinline__ short f2bfs(float x) {
  union { bf16 h; short s; } u; u.h = __float2bfloat16(x); return u.s;
}
static __device__ __forceinline__ float bfs2f(short s) {
  unsigned int u = ((unsigned int)(unsigned short)s) << 16;
  float f; __builtin_memcpy(&f, &u, 4); return f;
}

// ---------------- merged prologue: qkv/proj weight cvt + bias table ----------------
__global__ __launch_bounds__(256) void k_prep(const float* __restrict__ qkv_w,
    const float* __restrict__ proj_w, const float* __restrict__ rt,
    bf16* __restrict__ wq, bf16* __restrict__ wp, unsigned int* __restrict__ tbl)
{
  int i = blockIdx.x*256 + threadIdx.x;
  if (i < NQKVW) {
    wq[i] = __float2bfloat16(qkv_w[i]);
  } else if (i < NQKVW + NPROJW) {
    int j = i - NQKVW;
    wp[j] = __float2bfloat16(proj_w[j]);
  } else if (i < NQKVW + NPROJW + TBLN) {
    int idx = i - (NQKVW + NPROJW);
    int mp   = idx % TBLM;
    int rest = idx / TBLM;
    int n    = rest % NTOK;
    int head = rest / NTOK;
    unsigned int outv;
    if (mp >= NTOK) {
      outv = 0x0000FF80u;                        // lo = bf16 -inf, hi = 0
    } else {
      int ni = n / WSZ,  nj = n % WSZ;
      int mi = mp / WSZ, mj = mp % WSZ;
      int ridx = (ni - mi + 13)*27 + (nj - mj + 13);
      unsigned int lo = (unsigned short)f2bfs(rt[ridx*2*NHEAD + head]);
      unsigned int hi = (unsigned short)f2bfs(rt[ridx*2*NHEAD + NHEAD + head]);
      outv = lo | (hi << 16);
    }
    tbl[idx] = outv;
  }
}

// ---------------- merged fc weight convert (fc1 + fc2) ----------------
__global__ __launch_bounds__(256) void k_cvt2(const float* __restrict__ fc1_w,
    const float* __restrict__ fc2_w, bf16* __restrict__ wf1, bf16* __restrict__ wf2)
{
  int i = blockIdx.x*256 + threadIdx.x;
  if (i < NFCW) wf1[i] = __float2bfloat16(fc1_w[i]);
  else          wf2[i - NFCW] = __float2bfloat16(fc2_w[i - NFCW]);
}

// ---------------- LN: wave-per-row, vectorized, no LDS/barrier ----------------
template<bool WIN, typename TIN>
__global__ __launch_bounds__(256) void k_ln(const TIN* __restrict__ xin,
    const float* __restrict__ gw, const float* __restrict__ gb,
    bf16* __restrict__ out)
{
  int lane = threadIdx.x & 63, wid = threadIdx.x >> 6;
  int r = blockIdx.x*4 + wid;
  const TIN* xp = xin + (size_t)r * CDIM;
  float v[6];
  if constexpr (sizeof(TIN) == 4) {
    float4 a = *(const float4*)((const float*)xp + lane*4);
    float2 b = *(const float2*)((const float*)xp + 256 + lane*2);
    v[0]=a.x; v[1]=a.y; v[2]=a.z; v[3]=a.w; v[4]=b.x; v[5]=b.y;
  } else {
    s16x4 a = *(const s16x4*)((const short*)xp + lane*4);
    s16x2 b = *(const s16x2*)((const short*)xp + 256 + lane*2);
    v[0]=bfs2f(a[0]); v[1]=bfs2f(a[1]); v[2]=bfs2f(a[2]); v[3]=bfs2f(a[3]);
    v[4]=bfs2f(b[0]); v[5]=bfs2f(b[1]);
  }
  float s = 0.f, ss = 0.f;
  #pragma unroll
  for (int j = 0; j < 6; j++) { s += v[j]; ss += v[j]*v[j]; }
  #pragma unroll
  for (int o = 1; o < 64; o <<= 1) { s += __shfl_xor(s, o); ss += __shfl_xor(ss, o); }
  float mean = s * (1.0f/CDIM);
  float var  = ss * (1.0f/CDIM) - mean*mean;
  float rstd = rsqrtf(var + EPSLN);

  size_t orow;
  if (WIN) {
    int b = r / LDIM, l = r % LDIM;
    int h = l / WDIM, w = l % WDIM;
    int h2 = (h + HDIM - SSZ) % HDIM, w2 = (w + WDIM - SSZ) % WDIM;
    int wh = h2 / WSZ, ii = h2 % WSZ, ww = w2 / WSZ, jj = w2 % WSZ;
    int b_ = b*NWIN + wh*4 + ww;
    int n  = ii*WSZ + jj;
    orow = ((size_t)b_*NTOK + n) * CDIM;
  } else {
    orow = (size_t)r * CDIM;
  }
  float4 w4 = *(const float4*)(gw + lane*4);
  float2 w2 = *(const float2*)(gw + 256 + lane*2);
  float4 g4 = *(const float4*)(gb + lane*4);
  float2 g2 = *(const float2*)(gb + 256 + lane*2);
  s16x4 o4;
  o4[0] = f2bfs((v[0]-mean)*rstd*w4.x + g4.x);
  o4[1] = f2bfs((v[1]-mean)*rstd*w4.y + g4.y);
  o4[2] = f2bfs((v[2]-mean)*rstd*w4.z + g4.z);
  o4[3] = f2bfs((v[3]-mean)*rstd*w4.w + g4.w);
  *(s16x4*)((short*)out + orow + lane*4) = o4;
  s16x2 o2;
  o2[0] = f2bfs((v[4]-mean)*rstd*w2.x + g2.x);
  o2[1] = f2bfs((v[5]-mean)*rstd*w2.y + g2.y);
  *(s16x2*)((short*)out + orow + 256 + lane*2) = o2;
}

// ---------------- MFMA GEMM: C = A(bf16,MxK) @ Wb(bf16,NCxK)^T ----------------
// 256x128 tile, 512 threads (8 waves = 4M x 2N), BK=32, TRIPLE-buffered 72 KB
// LDS, single-barrier 2-tile-deep pipeline (T3/T4). Operand-SWAPPED MFMA +
// vector epilogue; both-sides XOR bank-swizzle; XCD-bijective grid swizzle.
// (Proven best across 11 structural variants; FROZEN.)
template<int KD, int EPI>
__global__ __launch_bounds__(512, 4) void k_mgemm(
    const bf16* __restrict__ A, const bf16* __restrict__ Wb,
    const float* __restrict__ bias, const float* __restrict__ aux,
    const bf16* __restrict__ auxb,
    float* __restrict__ outf, bf16* __restrict__ outb, int gx)
{
  __shared__ short As[3][256*32];   // 16 KB each
  __shared__ short Bs[3][128*32];   // 8 KB each  (total 72 KB)
  int tid  = threadIdx.x;
  int lane = tid & 63, wid = tid >> 6;
  int c15 = lane & 15, h4 = lane >> 4;
  int wr = wid >> 1, wc = wid & 1;          // 4 M-quarters x 2 N-halves

  int nwg = gridDim.x, bid = blockIdx.x;
  int swz = (bid & 7) * (nwg >> 3) + (bid >> 3);
  int ty = swz / gx, tx = swz - ty * gx;
  int row0 = ty * 256, col0 = tx * 128;

  f32x4 acc[4][4] = {};          // [n][m]

  int r0  = tid >> 2, b0 = tid & 3;
  int sk0 = (b0 ^ (r0 & 3) ^ ((r0 >> 2) & 3)) * 8;

  const int NT = KD / 32;

#define STAGE_T(k0, bf) do { \
    ASYNC16(A  + (size_t)(row0 + r0)*KD       + (k0) + sk0, &As[bf][tid*8]); \
    ASYNC16(A  + (size_t)(row0 + r0 + 128)*KD + (k0) + sk0, &As[bf][(tid+512)*8]); \
    ASYNC16(Wb + (size_t)(col0 + r0)*KD       + (k0) + sk0, &Bs[bf][tid*8]); \
  } while (0)

  STAGE_T(0, 0);                      // prologue: tiles 0,1 in flight
  STAGE_T(32, 1);

  int rblk = (h4 ^ (c15 & 3) ^ ((c15 >> 2) & 3)) * 8;   // swizzled read offset

  for (int t = 0; t < NT; t++) {
    int cur = t % 3;
    if (t + 1 < NT) {
      asm volatile("s_waitcnt vmcnt(3)" ::: "memory");   // own tile-t loads done
    } else {
      asm volatile("s_waitcnt vmcnt(0)" ::: "memory");
    }
    __builtin_amdgcn_s_barrier();     // tile t complete block-wide; buf[(t+2)%3] readers done
    __builtin_amdgcn_sched_barrier(0);

    if (t + 2 < NT) STAGE_T((t+2)*32, (t+2) % 3);

    bf16x8 af[4], bfr[4];
    #pragma unroll
    for (int m = 0; m < 4; m++)
      af[m] = *reinterpret_cast<const bf16x8*>(&As[cur][(wr*64 + m*16 + c15)*32 + rblk]);
    #pragma unroll
    for (int n = 0; n < 4; n++)
      bfr[n] = *reinterpret_cast<const bf16x8*>(&Bs[cur][(wc*64 + n*16 + c15)*32 + rblk]);
    __builtin_amdgcn_s_setprio(1);
    #pragma unroll
    for (int n = 0; n < 4; n++)
      #pragma unroll
      for (int m = 0; m < 4; m++)
        acc[n][m] = __builtin_amdgcn_mfma_f32_16x16x32_bf16(bfr[n], af[m], acc[n][m], 0, 0, 0);
    __builtin_amdgcn_s_setprio(0);
    __builtin_amdgcn_sched_barrier(0);
  }
#undef STAGE_T

  int rb = row0 + wr*64 + c15;
  int cb = col0 + wc*64 + h4*4;
  #pragma unroll
  for (int m = 0; m < 4; m++) {
    int r = rb + m*16;
    if constexpr (EPI == 0) {
      #pragma unroll
      for (int n = 0; n < 4; n++) {
        int c0 = cb + n*16;
        f32x4 v = acc[n][m];
        f32x4 b4 = *(const f32x4*)&bias[c0];
        float scl = (c0 < CDIM) ? ATTSCALE : 1.f;
        s16x4 o;
        #pragma unroll
        for (int i = 0; i < 4; i++) o[i] = f2bfs((v[i] + b4[i]) * scl);
        *(s16x4*)&outb[(size_t)r*QKVC + c0] = o;
      }
    } else if constexpr (EPI == 1) {
      int b_ = r / NTOK, nn = r % NTOK;
      int b = b_ >> 4, wi = b_ & 15, wh = wi >> 2, ww = wi & 3;
      int ii = nn / WSZ, jj = nn % WSZ;
      int hh = (wh*WSZ + ii + SSZ) % HDIM;
      int wcc = (ww*WSZ + jj + SSZ) % WDIM;
      size_t rr = ((size_t)b*LDIM + hh*WDIM + wcc) * CDIM;
      #pragma unroll
      for (int n = 0; n < 4; n++) {
        int c0 = cb + n*16;
        f32x4 v = acc[n][m];
        f32x4 b4 = *(const f32x4*)&bias[c0];
        f32x4 a4 = *(const f32x4*)&aux[rr + c0];
        s16x4 o;
        #pragma unroll
        for (int i = 0; i < 4; i++) o[i] = f2bfs(a4[i] + v[i] + b4[i]);
        *(s16x4*)&outb[rr + c0] = o;
      }
    } else if constexpr (EPI == 2) {
      #pragma unroll
      for (int n = 0; n < 4; n++) {
        int c0 = cb + n*16;
        f32x4 v = acc[n][m];
        f32x4 b4 = *(const f32x4*)&bias[c0];
        s16x4 o;
        #pragma unroll
        for (int i = 0; i < 4; i++) {
          float val = v[i] + b4[i];
          val = 0.5f * val * (1.0f + erff(val * 0.70710678118654752f));
          o[i] = f2bfs(val);
        }
        *(s16x4*)&outb[(size_t)r*HIDDIM + c0] = o;
      }
    } else {
      #pragma unroll
      for (int n = 0; n < 4; n++) {
        int c0 = cb + n*16;
        f32x4 v = acc[n][m];
        f32x4 b4 = *(const f32x4*)&bias[c0];
        s16x4 ab = *(const s16x4*)&auxb[(size_t)r*CDIM + c0];
        f32x4 o;
        #pragma unroll
        for (int i = 0; i < 4; i++) o[i] = v[i] + b4[i] + bfs2f(ab[i]);
        *(f32x4*)&outf[(size_t)r*CDIM + c0] = o;
      }
    }
  }
}

// ---------------- MFMA fused window attention (register-resident P) ----------------
// Swapped QK^T (mfma(kf,qf) -> S^T; softmax column n lane-resident); softmax
// fused into the t-loop; unnormalized bf16 pf[13] feeds 16x16x16 PV MFMA.
// Bias/rscale from the per-HEAD global table (one aligned uint4 per t; -inf
// pad rows subsume m>=196 masking). Window-edge specialization (9/16 windows
// mask-free). launch_bounds (256,2) — proven best.
__global__ __launch_bounds__(256, 2) void k_attn_mfma(const bf16* __restrict__ qkv,
    const unsigned int* __restrict__ tbl, bf16* __restrict__ out)
{
  __shared__ short  Ks[208*KROW];   // [m][k], rows 196..207 zero, padded stride
  __shared__ short  Vt[32*VROW];    // [d][m], cols 196..223 zero, padded stride

  int blk = blockIdx.x;
  int b_ = blk / NHEAD, head = blk % NHEAD;
  int tid = threadIdx.x, lane = tid & 63, wid = tid >> 6;
  int c15 = lane & 15, h4 = lane >> 4;

  // ---- staging ----
  const bf16* rowbase = qkv + (size_t)b_*NTOK*QKVC + head*HDHEAD;
  const bf16* kp = rowbase + CDIM;      // k block
  const bf16* vp = rowbase + 2*CDIM;    // v block
  for (int c = tid; c < 784; c += 256) {          // 196 rows x 4 chunks of 8
    int m = c >> 2, k8 = (c & 3) * 8;
    *(bf16x8*)&Ks[m*KROW + k8] = *(const bf16x8*)(kp + (size_t)m*QKVC + k8);
    bf16x8 vv = *(const bf16x8*)(vp + (size_t)m*QKVC + k8);
    #pragma unroll
    for (int j = 0; j < 8; j++) Vt[(k8+j)*VROW + m] = vv[j];
  }
  for (int e = tid; e < 12*KROW; e += 256) Ks[196*KROW + e] = 0;
  for (int e = tid; e < 32*28; e += 256) Vt[(e/28)*VROW + 196 + (e%28)] = 0;
  __syncthreads();

  int wi = b_ & 15, wh = wi >> 2, ww = wi & 3;
  int whb = wh*WSZ, wwb = ww*WSZ;
  bool edgewin = (wh == 3) || (ww == 3);   // block-uniform: mask can be nonzero

  const unsigned int* thead = tbl + (size_t)head*NTOK*TBLM;

  bf16* op = out + (size_t)b_*NTOK*CDIM + head*HDHEAD;

  for (int s = wid; s < 13; s += 4) {             // wave-independent strips
    int n = s*16 + c15;
    int ncl = min(n, NTOK-1);
    bf16x8 qf = *(const bf16x8*)(rowbase + (size_t)ncl*QKVC + h4*8);
    const unsigned int* trow = thead + (size_t)ncl*TBLM;

    float sum = 0.f;
    s16x4 pf[13];                                  // unnormalized bf16 P

    if (edgewin) {
      int ni = ncl / 14, nj = ncl - (ncl/14)*14;
      int nreg = ((whb + ni) < 42 ? 0 : ((whb + ni) < 49 ? 1 : 2))*3
               + ((wwb + nj) < 42 ? 0 : ((wwb + nj) < 49 ? 1 : 2));
      #pragma unroll
      for (int t = 0; t < 13; t++) {
        bf16x8 kf = *(const bf16x8*)&Ks[(t*16 + c15)*KROW + h4*8];
        f32x4 sct = __builtin_amdgcn_mfma_f32_16x16x32_bf16(kf, qf, (f32x4){0.f,0.f,0.f,0.f}, 0, 0, 0);

        int m0 = t*16 + h4*4;
        u32x4 tv = *(const u32x4*)&trow[m0];       // 16B aligned, linear m'
        int mi = m0 / 14, mj = m0 - (m0/14)*14;
        #pragma unroll
        for (int i = 0; i < 4; i++) {
          int ha = whb + mi, wa = wwb + mj;
          int mr = (ha < 42 ? 0 : (ha < 49 ? 1 : 2))*3
                 + (wa < 42 ? 0 : (wa < 49 ? 1 : 2));
          float sv = sct[i] + bfs2f((short)(tv[i] & 0xFFFFu));
          if (mr != nreg) sv -= 100.f;
          float e = __expf(sv);                    // no-max softmax; -inf -> 0
          sum += e;
          pf[t][i] = f2bfs(e * bfs2f((short)(tv[i] >> 16)));   // fold rscale
          mj++; bool w = (mj == 14); mj = w ? 0 : mj; mi += w ? 1 : 0;
        }
      }
    } else {
      // interior window: mask == 0 everywhere; no region math needed
      #pragma unroll
      for (int t = 0; t < 13; t++) {
        bf16x8 kf = *(const bf16x8*)&Ks[(t*16 + c15)*KROW + h4*8];
        f32x4 sct = __builtin_amdgcn_mfma_f32_16x16x32_bf16(kf, qf, (f32x4){0.f,0.f,0.f,0.f}, 0, 0, 0);

        u32x4 tv = *(const u32x4*)&trow[t*16 + h4*4];
        #pragma unroll
        for (int i = 0; i < 4; i++) {
          float e = __expf(sct[i] + bfs2f((short)(tv[i] & 0xFFFFu)));
          sum += e;
          pf[t][i] = f2bfs(e * bfs2f((short)(tv[i] >> 16)));   // fold rscale
        }
      }
    }

    sum += __shfl_xor(sum, 16);
    sum += __shfl_xor(sum, 32);
    float inv = 1.f / sum;

    // PV: O^T[d][n] via 16x16x16 MFMA, A = Vt rows (d), B = pf (unnormalized)
    f32x4 o0 = {0.f,0.f,0.f,0.f}, o1 = {0.f,0.f,0.f,0.f};
    #pragma unroll
    for (int t = 0; t < 13; t++) {
      s16x4 va = *(const s16x4*)&Vt[c15*VROW + t*16 + h4*4];
      s16x4 vb = *(const s16x4*)&Vt[(16 + c15)*VROW + t*16 + h4*4];
      o0 = MFMA16(va, pf[t], o0);
      o1 = MFMA16(vb, pf[t], o1);
    }

    if (n < NTOK) {
      s16x4 w0, w1;
      #pragma unroll
      for (int i = 0; i < 4; i++) {
        w0[i] = f2bfs(o0[i] * inv);
        w1[i] = f2bfs(o1[i] * inv);
      }
      *(s16x4*)((short*)op + (size_t)n*CDIM + h4*4)      = w0;
      *(s16x4*)((short*)op + (size_t)n*CDIM + 16 + h4*4) = w1;
    }
  }
}

// ---------------- launch ----------------
extern "C" void kernel_launch(void* const* d_in, const int* in_sizes, int n_in,
                              void* d_out, int out_size, void* d_ws, size_t ws_size,
                              hipStream_t stream)
{
  const float* x      = (const float*)d_in[0];
  const float* n1w    = (const float*)d_in[1];
  const float* n1b    = (const float*)d_in[2];
  const float* qkv_w  = (const float*)d_in[3];
  const float* qkv_b  = (const float*)d_in[4];
  const float* proj_w = (const float*)d_in[5];
  const float* proj_b = (const float*)d_in[6];
  const float* rt     = (const float*)d_in[7];
  const float* n2w    = (const float*)d_in[8];
  const float* n2b    = (const float*)d_in[9];
  const float* fc1_w  = (const float*)d_in[10];
  const float* fc1_b  = (const float*)d_in[11];
  const float* fc2_w  = (const float*)d_in[12];
  const float* fc2_b  = (const float*)d_in[13];

  char* ws = (char*)d_ws;
  const size_t SZ_BF = (size_t)MROWS * CDIM * 2;   // 77,070,336 B
  // arena (total exactly 8*SZ_BF, proven footprint):
  //  R0 [0,1SZ):    xw -> attnout -> (after proj) wf1,wf2
  //  R1 [1SZ,4SZ):  qkv (contiguous [r][1152]) -> x2(bf16,[1SZ,2SZ)) + hln([2SZ,3SZ))
  //  R2 [4SZ,8SZ):  wq,wp (at 4SZ) + tbl (at 5SZ, dead before fc1) -> hid
  bf16*  xw      = (bf16*)ws;
  bf16*  attnout = (bf16*)ws;
  bf16*  qkv     = (bf16*)(ws + SZ_BF);
  bf16*  x2b     = (bf16*)(ws + SZ_BF);
  bf16*  hln     = (bf16*)(ws + 2*SZ_BF);
  bf16*  hid     = (bf16*)(ws + 4*SZ_BF);
  bf16* wq  = (bf16*)(ws + 4*SZ_BF);  // lives in R2 until fc1 clobbers it
  bf16* wp  = wq + NQKVW;
  bf16* wf1 = (bf16*)ws;              // converted into R0 after proj GEMM
  bf16* wf2 = wf1 + NFCW;
  unsigned int* tbl = (unsigned int*)(ws + 5*SZ_BF);  // 2.1 MB, dead at fc1

  k_prep<<<(NQKVW + NPROJW + TBLN + 255)/256, 256, 0, stream>>>(
      qkv_w, proj_w, rt, wq, wp, tbl);

  k_ln<true, float><<<MROWS/4, 256, 0, stream>>>(x, n1w, n1b, xw);
  k_mgemm<CDIM, 0><<<(MROWS/256)*9, 512, 0, stream>>>(
      xw, wq, qkv_b, nullptr, nullptr, nullptr, qkv, 9);
  k_attn_mfma<<<BWIN*NHEAD, 256, 0, stream>>>(qkv, tbl, attnout);
  k_mgemm<CDIM, 1><<<(MROWS/256)*3, 512, 0, stream>>>(
      attnout, wp, proj_b, x, nullptr, nullptr, x2b, 3);

  k_cvt2<<<(2*NFCW)/256, 256, 0, stream>>>(fc1_w, fc2_w, wf1, wf2);

  k_ln<false, bf16><<<MROWS/4, 256, 0, stream>>>(x2b, n2w, n2b, hln);
  k_mgemm<CDIM, 2><<<(MROWS/256)*12, 512, 0, stream>>>(
      hln, wf1, fc1_b, nullptr, nullptr, nullptr, hid, 12);
  k_mgemm<HIDDIM, 3><<<(MROWS/256)*3, 512, 0, stream>>>(
      hid, wf2, fc2_b, nullptr, x2b, (float*)d_out, nullptr, 3);
}

// Round 29
// 970.687 us; speedup vs baseline: 1.0310x; 1.0026x over previous
//
#include <hip/hip_runtime.h>
#include <hip/hip_bf16.h>
#include <math.h>

// ---------------- problem constants ----------------
#define BDIM 32
#define HDIM 56
#define WDIM 56
#define CDIM 384
#define NHEAD 12
#define WSZ 14
#define SSZ 7
#define LDIM (HDIM*WDIM)        // 3136
#define NTOK (WSZ*WSZ)          // 196
#define HDHEAD (CDIM/NHEAD)     // 32
#define HIDDIM (4*CDIM)         // 1536
#define NWIN 16
#define BWIN (BDIM*NWIN)        // 512
#define MROWS (BDIM*LDIM)       // 100352 == BWIN*NTOK
#define EPSLN 1e-5f
#define ATTSCALE 0.17677669529663687f   // 32^-0.5
#define QKVC (3*CDIM)           // 1152, contiguous qkv row stride
#define TBLM 224                // bias table m' extent (196 real + -inf pad)
#define NQKVW (3*CDIM*CDIM)     // 442368
#define NPROJW (CDIM*CDIM)      // 147456
#define NFCW  (HIDDIM*CDIM)     // 589824
#define TBLN  (NHEAD*NTOK*TBLM) // 526848

// padded LDS strides (shorts) for attention
#define KROW 40
#define VROW 232

typedef __hip_bfloat16 bf16;
typedef __attribute__((ext_vector_type(8))) short bf16x8;   // 8 bf16 = 4 VGPRs
typedef __attribute__((ext_vector_type(4))) short s16x4;    // 4 bf16 = 1 b64
typedef __attribute__((ext_vector_type(2))) short s16x2;
typedef __attribute__((ext_vector_type(4))) float f32x4;
typedef __attribute__((ext_vector_type(4))) unsigned int u32x4;

// v_mfma_f32_16x16x16_bf16 (gfx950; A/B = 2 VGPRs = 4 bf16). Clang builtin is
// the gfx90a-era "...16x16x16bf16_1k" name. Host pass can't see target
// builtins — gate on device compile; host stub only parses, never executes.
#if defined(__HIP_DEVICE_COMPILE__)
#define MFMA16(a,b,c) __builtin_amdgcn_mfma_f32_16x16x16bf16_1k(a,b,c,0,0,0)
#else
#define MFMA16(a,b,c) (c)
#endif

// async global->LDS, 16B per lane, wave-uniform LDS base
#define ASYNC16(gp, lp) __builtin_amdgcn_global_load_lds( \
    (__attribute__((address_space(1))) void*)(gp),        \
    (__attribute__((address_space(3))) void*)(lp), 16, 0, 0)

// float -> bf16 bit pattern as short (type-consistent with short LDS arrays)
static __device__ __forceinline__ short f2bfs(float x) {
  union { bf16 h; short s; } u; u.h = __float2bfloat16(x); return u.s;
}
static __device__ __forceinline__ float bfs2f(short s) {
  unsigned int u = ((unsigned int)(unsigned short)s) << 16;
  float f; __builtin_memcpy(&f, &u, 4); return f;
}

// ---------------- merged prologue: qkv/proj weight cvt + bias table ----------------
__global__ __launch_bounds__(256) void k_prep(const float* __restrict__ qkv_w,
    const float* __restrict__ proj_w, const float* __restrict__ rt,
    bf16* __restrict__ wq, bf16* __restrict__ wp, unsigned int* __restrict__ tbl)
{
  int i = blockIdx.x*256 + threadIdx.x;
  if (i < NQKVW) {
    wq[i] = __float2bfloat16(qkv_w[i]);
  } else if (i < NQKVW + NPROJW) {
    int j = i - NQKVW;
    wp[j] = __float2bfloat16(proj_w[j]);
  } else if (i < NQKVW + NPROJW + TBLN) {
    int idx = i - (NQKVW + NPROJW);
    int mp   = idx % TBLM;
    int rest = idx / TBLM;
    int n    = rest % NTOK;
    int head = rest / NTOK;
    unsigned int outv;
    if (mp >= NTOK) {
      outv = 0x0000FF80u;                        // lo = bf16 -inf, hi = 0
    } else {
      int ni = n / WSZ,  nj = n % WSZ;
      int mi = mp / WSZ, mj = mp % WSZ;
      int ridx = (ni - mi + 13)*27 + (nj - mj + 13);
      unsigned int lo = (unsigned short)f2bfs(rt[ridx*2*NHEAD + head]);
      unsigned int hi = (unsigned short)f2bfs(rt[ridx*2*NHEAD + NHEAD + head]);
      outv = lo | (hi << 16);
    }
    tbl[idx] = outv;
  }
}

// ---------------- merged fc weight convert (fc1 + fc2) ----------------
__global__ __launch_bounds__(256) void k_cvt2(const float* __restrict__ fc1_w,
    const float* __restrict__ fc2_w, bf16* __restrict__ wf1, bf16* __restrict__ wf2)
{
  int i = blockIdx.x*256 + threadIdx.x;
  if (i < NFCW) wf1[i] = __float2bfloat16(fc1_w[i]);
  else          wf2[i - NFCW] = __float2bfloat16(fc2_w[i - NFCW]);
}

// ---------------- LN: wave-per-row, vectorized, no LDS/barrier ----------------
template<bool WIN, typename TIN>
__global__ __launch_bounds__(256) void k_ln(const TIN* __restrict__ xin,
    const float* __restrict__ gw, const float* __restrict__ gb,
    bf16* __restrict__ out)
{
  int lane = threadIdx.x & 63, wid = threadIdx.x >> 6;
  int r = blockIdx.x*4 + wid;
  const TIN* xp = xin + (size_t)r * CDIM;
  float v[6];
  if constexpr (sizeof(TIN) == 4) {
    float4 a = *(const float4*)((const float*)xp + lane*4);
    float2 b = *(const float2*)((const float*)xp + 256 + lane*2);
    v[0]=a.x; v[1]=a.y; v[2]=a.z; v[3]=a.w; v[4]=b.x; v[5]=b.y;
  } else {
    s16x4 a = *(const s16x4*)((const short*)xp + lane*4);
    s16x2 b = *(const s16x2*)((const short*)xp + 256 + lane*2);
    v[0]=bfs2f(a[0]); v[1]=bfs2f(a[1]); v[2]=bfs2f(a[2]); v[3]=bfs2f(a[3]);
    v[4]=bfs2f(b[0]); v[5]=bfs2f(b[1]);
  }
  float s = 0.f, ss = 0.f;
  #pragma unroll
  for (int j = 0; j < 6; j++) { s += v[j]; ss += v[j]*v[j]; }
  #pragma unroll
  for (int o = 1; o < 64; o <<= 1) { s += __shfl_xor(s, o); ss += __shfl_xor(ss, o); }
  float mean = s * (1.0f/CDIM);
  float var  = ss * (1.0f/CDIM) - mean*mean;
  float rstd = rsqrtf(var + EPSLN);

  size_t orow;
  if (WIN) {
    int b = r / LDIM, l = r % LDIM;
    int h = l / WDIM, w = l % WDIM;
    int h2 = (h + HDIM - SSZ) % HDIM, w2 = (w + WDIM - SSZ) % WDIM;
    int wh = h2 / WSZ, ii = h2 % WSZ, ww = w2 / WSZ, jj = w2 % WSZ;
    int b_ = b*NWIN + wh*4 + ww;
    int n  = ii*WSZ + jj;
    orow = ((size_t)b_*NTOK + n) * CDIM;
  } else {
    orow = (size_t)r * CDIM;
  }
  float4 w4 = *(const float4*)(gw + lane*4);
  float2 w2 = *(const float2*)(gw + 256 + lane*2);
  float4 g4 = *(const float4*)(gb + lane*4);
  float2 g2 = *(const float2*)(gb + 256 + lane*2);
  s16x4 o4;
  o4[0] = f2bfs((v[0]-mean)*rstd*w4.x + g4.x);
  o4[1] = f2bfs((v[1]-mean)*rstd*w4.y + g4.y);
  o4[2] = f2bfs((v[2]-mean)*rstd*w4.z + g4.z);
  o4[3] = f2bfs((v[3]-mean)*rstd*w4.w + g4.w);
  *(s16x4*)((short*)out + orow + lane*4) = o4;
  s16x2 o2;
  o2[0] = f2bfs((v[4]-mean)*rstd*w2.x + g2.x);
  o2[1] = f2bfs((v[5]-mean)*rstd*w2.y + g2.y);
  *(s16x2*)((short*)out + orow + 256 + lane*2) = o2;
}

// ---------------- MFMA GEMM: C = A(bf16,MxK) @ Wb(bf16,NCxK)^T ----------------
// 256x128 tile, 512 threads (8 waves = 4M x 2N), BK=32, TRIPLE-buffered 72 KB
// LDS, single-barrier 2-tile-deep pipeline (T3/T4). Operand-SWAPPED MFMA +
// vector epilogue; both-sides XOR bank-swizzle; XCD-bijective grid swizzle.
// (Proven best across 11 structural variants; FROZEN.)
template<int KD, int EPI>
__global__ __launch_bounds__(512, 4) void k_mgemm(
    const bf16* __restrict__ A, const bf16* __restrict__ Wb,
    const float* __restrict__ bias, const float* __restrict__ aux,
    const bf16* __restrict__ auxb,
    float* __restrict__ outf, bf16* __restrict__ outb, int gx)
{
  __shared__ short As[3][256*32];   // 16 KB each
  __shared__ short Bs[3][128*32];   // 8 KB each  (total 72 KB)
  int tid  = threadIdx.x;
  int lane = tid & 63, wid = tid >> 6;
  int c15 = lane & 15, h4 = lane >> 4;
  int wr = wid >> 1, wc = wid & 1;          // 4 M-quarters x 2 N-halves

  int nwg = gridDim.x, bid = blockIdx.x;
  int swz = (bid & 7) * (nwg >> 3) + (bid >> 3);
  int ty = swz / gx, tx = swz - ty * gx;
  int row0 = ty * 256, col0 = tx * 128;

  f32x4 acc[4][4] = {};          // [n][m]

  int r0  = tid >> 2, b0 = tid & 3;
  int sk0 = (b0 ^ (r0 & 3) ^ ((r0 >> 2) & 3)) * 8;

  const int NT = KD / 32;

#define STAGE_T(k0, bf) do { \
    ASYNC16(A  + (size_t)(row0 + r0)*KD       + (k0) + sk0, &As[bf][tid*8]); \
    ASYNC16(A  + (size_t)(row0 + r0 + 128)*KD + (k0) + sk0, &As[bf][(tid+512)*8]); \
    ASYNC16(Wb + (size_t)(col0 + r0)*KD       + (k0) + sk0, &Bs[bf][tid*8]); \
  } while (0)

  STAGE_T(0, 0);                      // prologue: tiles 0,1 in flight
  STAGE_T(32, 1);

  int rblk = (h4 ^ (c15 & 3) ^ ((c15 >> 2) & 3)) * 8;   // swizzled read offset

  for (int t = 0; t < NT; t++) {
    int cur = t % 3;
    if (t + 1 < NT) {
      asm volatile("s_waitcnt vmcnt(3)" ::: "memory");   // own tile-t loads done
    } else {
      asm volatile("s_waitcnt vmcnt(0)" ::: "memory");
    }
    __builtin_amdgcn_s_barrier();     // tile t complete block-wide; buf[(t+2)%3] readers done
    __builtin_amdgcn_sched_barrier(0);

    if (t + 2 < NT) STAGE_T((t+2)*32, (t+2) % 3);

    bf16x8 af[4], bfr[4];
    #pragma unroll
    for (int m = 0; m < 4; m++)
      af[m] = *reinterpret_cast<const bf16x8*>(&As[cur][(wr*64 + m*16 + c15)*32 + rblk]);
    #pragma unroll
    for (int n = 0; n < 4; n++)
      bfr[n] = *reinterpret_cast<const bf16x8*>(&Bs[cur][(wc*64 + n*16 + c15)*32 + rblk]);
    __builtin_amdgcn_s_setprio(1);
    #pragma unroll
    for (int n = 0; n < 4; n++)
      #pragma unroll
      for (int m = 0; m < 4; m++)
        acc[n][m] = __builtin_amdgcn_mfma_f32_16x16x32_bf16(bfr[n], af[m], acc[n][m], 0, 0, 0);
    __builtin_amdgcn_s_setprio(0);
    __builtin_amdgcn_sched_barrier(0);
  }
#undef STAGE_T

  int rb = row0 + wr*64 + c15;
  int cb = col0 + wc*64 + h4*4;
  #pragma unroll
  for (int m = 0; m < 4; m++) {
    int r = rb + m*16;
    if constexpr (EPI == 0) {
      #pragma unroll
      for (int n = 0; n < 4; n++) {
        int c0 = cb + n*16;
        f32x4 v = acc[n][m];
        f32x4 b4 = *(const f32x4*)&bias[c0];
        float scl = (c0 < CDIM) ? ATTSCALE : 1.f;
        s16x4 o;
        #pragma unroll
        for (int i = 0; i < 4; i++) o[i] = f2bfs((v[i] + b4[i]) * scl);
        *(s16x4*)&outb[(size_t)r*QKVC + c0] = o;
      }
    } else if constexpr (EPI == 1) {
      int b_ = r / NTOK, nn = r % NTOK;
      int b = b_ >> 4, wi = b_ & 15, wh = wi >> 2, ww = wi & 3;
      int ii = nn / WSZ, jj = nn % WSZ;
      int hh = (wh*WSZ + ii + SSZ) % HDIM;
      int wcc = (ww*WSZ + jj + SSZ) % WDIM;
      size_t rr = ((size_t)b*LDIM + hh*WDIM + wcc) * CDIM;
      #pragma unroll
      for (int n = 0; n < 4; n++) {
        int c0 = cb + n*16;
        f32x4 v = acc[n][m];
        f32x4 b4 = *(const f32x4*)&bias[c0];
        f32x4 a4 = *(const f32x4*)&aux[rr + c0];
        s16x4 o;
        #pragma unroll
        for (int i = 0; i < 4; i++) o[i] = f2bfs(a4[i] + v[i] + b4[i]);
        *(s16x4*)&outb[rr + c0] = o;
      }
    } else if constexpr (EPI == 2) {
      #pragma unroll
      for (int n = 0; n < 4; n++) {
        int c0 = cb + n*16;
        f32x4 v = acc[n][m];
        f32x4 b4 = *(const f32x4*)&bias[c0];
        s16x4 o;
        #pragma unroll
        for (int i = 0; i < 4; i++) {
          float val = v[i] + b4[i];
          val = 0.5f * val * (1.0f + erff(val * 0.70710678118654752f));
          o[i] = f2bfs(val);
        }
        *(s16x4*)&outb[(size_t)r*HIDDIM + c0] = o;
      }
    } else {
      #pragma unroll
      for (int n = 0; n < 4; n++) {
        int c0 = cb + n*16;
        f32x4 v = acc[n][m];
        f32x4 b4 = *(const f32x4*)&bias[c0];
        s16x4 ab = *(const s16x4*)&auxb[(size_t)r*CDIM + c0];
        f32x4 o;
        #pragma unroll
        for (int i = 0; i < 4; i++) o[i] = v[i] + b4[i] + bfs2f(ab[i]);
        *(f32x4*)&outf[(size_t)r*CDIM + c0] = o;
      }
    }
  }
}

// ---------------- MFMA fused window attention (register-resident P) ----------------
// Swapped QK^T (mfma(kf,qf) -> S^T; softmax column n lane-resident); softmax
// fused into the t-loop; unnormalized bf16 pf[13] feeds 16x16x16 PV MFMA.
// Bias/rscale from the per-HEAD global table (one aligned uint4 per t; -inf
// pad rows subsume m>=196 masking). Window-edge specialization (9/16 windows
// mask-free). launch_bounds (256,2) — proven best.
__global__ __launch_bounds__(256, 2) void k_attn_mfma(const bf16* __restrict__ qkv,
    const unsigned int* __restrict__ tbl, bf16* __restrict__ out)
{
  __shared__ short  Ks[208*KROW];   // [m][k], rows 196..207 zero, padded stride
  __shared__ short  Vt[32*VROW];    // [d][m], cols 196..223 zero, padded stride

  int blk = blockIdx.x;
  int b_ = blk / NHEAD, head = blk % NHEAD;
  int tid = threadIdx.x, lane = tid & 63, wid = tid >> 6;
  int c15 = lane & 15, h4 = lane >> 4;

  // ---- staging ----
  const bf16* rowbase = qkv + (size_t)b_*NTOK*QKVC + head*HDHEAD;
  const bf16* kp = rowbase + CDIM;      // k block
  const bf16* vp = rowbase + 2*CDIM;    // v block
  for (int c = tid; c < 784; c += 256) {          // 196 rows x 4 chunks of 8
    int m = c >> 2, k8 = (c & 3) * 8;
    *(bf16x8*)&Ks[m*KROW + k8] = *(const bf16x8*)(kp + (size_t)m*QKVC + k8);
    bf16x8 vv = *(const bf16x8*)(vp + (size_t)m*QKVC + k8);
    #pragma unroll
    for (int j = 0; j < 8; j++) Vt[(k8+j)*VROW + m] = vv[j];
  }
  for (int e = tid; e < 12*KROW; e += 256) Ks[196*KROW + e] = 0;
  for (int e = tid; e < 32*28; e += 256) Vt[(e/28)*VROW + 196 + (e%28)] = 0;
  __syncthreads();

  int wi = b_ & 15, wh = wi >> 2, ww = wi & 3;
  int whb = wh*WSZ, wwb = ww*WSZ;
  bool edgewin = (wh == 3) || (ww == 3);   // block-uniform: mask can be nonzero

  const unsigned int* thead = tbl + (size_t)head*NTOK*TBLM;

  bf16* op = out + (size_t)b_*NTOK*CDIM + head*HDHEAD;

  for (int s = wid; s < 13; s += 4) {             // wave-independent strips
    int n = s*16 + c15;
    int ncl = min(n, NTOK-1);
    bf16x8 qf = *(const bf16x8*)(rowbase + (size_t)ncl*QKVC + h4*8);
    const unsigned int* trow = thead + (size_t)ncl*TBLM;

    float sum = 0.f;
    s16x4 pf[13];                                  // unnormalized bf16 P

    if (edgewin) {
      int ni = ncl / 14, nj = ncl - (ncl/14)*14;
      int nreg = ((whb + ni) < 42 ? 0 : ((whb + ni) < 49 ? 1 : 2))*3
               + ((wwb + nj) < 42 ? 0 : ((wwb + nj) < 49 ? 1 : 2));
      #pragma unroll
      for (int t = 0; t < 13; t++) {
        bf16x8 kf = *(const bf16x8*)&Ks[(t*16 + c15)*KROW + h4*8];
        f32x4 sct = __builtin_amdgcn_mfma_f32_16x16x32_bf16(kf, qf, (f32x4){0.f,0.f,0.f,0.f}, 0, 0, 0);

        int m0 = t*16 + h4*4;
        u32x4 tv = *(const u32x4*)&trow[m0];       // 16B aligned, linear m'
        int mi = m0 / 14, mj = m0 - (m0/14)*14;
        #pragma unroll
        for (int i = 0; i < 4; i++) {
          int ha = whb + mi, wa = wwb + mj;
          int mr = (ha < 42 ? 0 : (ha < 49 ? 1 : 2))*3
                 + (wa < 42 ? 0 : (wa < 49 ? 1 : 2));
          float sv = sct[i] + bfs2f((short)(tv[i] & 0xFFFFu));
          if (mr != nreg) sv -= 100.f;
          float e = __expf(sv);                    // no-max softmax; -inf -> 0
          sum += e;
          pf[t][i] = f2bfs(e * bfs2f((short)(tv[i] >> 16)));   // fold rscale
          mj++; bool w = (mj == 14); mj = w ? 0 : mj; mi += w ? 1 : 0;
        }
      }
    } else {
      // interior window: mask == 0 everywhere; no region math needed
      #pragma unroll
      for (int t = 0; t < 13; t++) {
        bf16x8 kf = *(const bf16x8*)&Ks[(t*16 + c15)*KROW + h4*8];
        f32x4 sct = __builtin_amdgcn_mfma_f32_16x16x32_bf16(kf, qf, (f32x4){0.f,0.f,0.f,0.f}, 0, 0, 0);

        u32x4 tv = *(const u32x4*)&trow[t*16 + h4*4];
        #pragma unroll
        for (int i = 0; i < 4; i++) {
          float e = __expf(sct[i] + bfs2f((short)(tv[i] & 0xFFFFu)));
          sum += e;
          pf[t][i] = f2bfs(e * bfs2f((short)(tv[i] >> 16)));   // fold rscale
        }
      }
    }

    sum += __shfl_xor(sum, 16);
    sum += __shfl_xor(sum, 32);
    float inv = 1.f / sum;

    // PV: O^T[d][n] via 16x16x16 MFMA, A = Vt rows (d), B = pf (unnormalized)
    f32x4 o0 = {0.f,0.f,0.f,0.f}, o1 = {0.f,0.f,0.f,0.f};
    #pragma unroll
    for (int t = 0; t < 13; t++) {
      s16x4 va = *(const s16x4*)&Vt[c15*VROW + t*16 + h4*4];
      s16x4 vb = *(const s16x4*)&Vt[(16 + c15)*VROW + t*16 + h4*4];
      o0 = MFMA16(va, pf[t], o0);
      o1 = MFMA16(vb, pf[t], o1);
    }

    if (n < NTOK) {
      s16x4 w0, w1;
      #pragma unroll
      for (int i = 0; i < 4; i++) {
        w0[i] = f2bfs(o0[i] * inv);
        w1[i] = f2bfs(o1[i] * inv);
      }
      *(s16x4*)((short*)op + (size_t)n*CDIM + h4*4)      = w0;
      *(s16x4*)((short*)op + (size_t)n*CDIM + 16 + h4*4) = w1;
    }
  }
}

// ---------------- launch ----------------
extern "C" void kernel_launch(void* const* d_in, const int* in_sizes, int n_in,
                              void* d_out, int out_size, void* d_ws, size_t ws_size,
                              hipStream_t stream)
{
  const float* x      = (const float*)d_in[0];
  const float* n1w    = (const float*)d_in[1];
  const float* n1b    = (const float*)d_in[2];
  const float* qkv_w  = (const float*)d_in[3];
  const float* qkv_b  = (const float*)d_in[4];
  const float* proj_w = (const float*)d_in[5];
  const float* proj_b = (const float*)d_in[6];
  const float* rt     = (const float*)d_in[7];
  const float* n2w    = (const float*)d_in[8];
  const float* n2b    = (const float*)d_in[9];
  const float* fc1_w  = (const float*)d_in[10];
  const float* fc1_b  = (const float*)d_in[11];
  const float* fc2_w  = (const float*)d_in[12];
  const float* fc2_b  = (const float*)d_in[13];

  char* ws = (char*)d_ws;
  const size_t SZ_BF = (size_t)MROWS * CDIM * 2;   // 77,070,336 B
  // arena (total exactly 8*SZ_BF, proven footprint):
  //  R0 [0,1SZ):    xw -> attnout -> (after proj) wf1,wf2
  //  R1 [1SZ,4SZ):  qkv (contiguous [r][1152]) -> x2(bf16,[1SZ,2SZ)) + hln([2SZ,3SZ))
  //  R2 [4SZ,8SZ):  wq,wp (at 4SZ) + tbl (at 5SZ, dead before fc1) -> hid
  bf16*  xw      = (bf16*)ws;
  bf16*  attnout = (bf16*)ws;
  bf16*  qkv     = (bf16*)(ws + SZ_BF);
  bf16*  x2b     = (bf16*)(ws + SZ_BF);
  bf16*  hln     = (bf16*)(ws + 2*SZ_BF);
  bf16*  hid     = (bf16*)(ws + 4*SZ_BF);
  bf16* wq  = (bf16*)(ws + 4*SZ_BF);  // lives in R2 until fc1 clobbers it
  bf16* wp  = wq + NQKVW;
  bf16* wf1 = (bf16*)ws;              // converted into R0 after proj GEMM
  bf16* wf2 = wf1 + NFCW;
  unsigned int* tbl = (unsigned int*)(ws + 5*SZ_BF);  // 2.1 MB, dead at fc1

  k_prep<<<(NQKVW + NPROJW + TBLN + 255)/256, 256, 0, stream>>>(
      qkv_w, proj_w, rt, wq, wp, tbl);

  k_ln<true, float><<<MROWS/4, 256, 0, stream>>>(x, n1w, n1b, xw);
  k_mgemm<CDIM, 0><<<(MROWS/256)*9, 512, 0, stream>>>(
      xw, wq, qkv_b, nullptr, nullptr, nullptr, qkv, 9);
  k_attn_mfma<<<BWIN*NHEAD, 256, 0, stream>>>(qkv, tbl, attnout);
  k_mgemm<CDIM, 1><<<(MROWS/256)*3, 512, 0, stream>>>(
      attnout, wp, proj_b, x, nullptr, nullptr, x2b, 3);

  k_cvt2<<<(2*NFCW)/256, 256, 0, stream>>>(fc1_w, fc2_w, wf1, wf2);

  k_ln<false, bf16><<<MROWS/4, 256, 0, stream>>>(x2b, n2w, n2b, hln);
  k_mgemm<CDIM, 2><<<(MROWS/256)*12, 512, 0, stream>>>(
      hln, wf1, fc1_b, nullptr, nullptr, nullptr, hid, 12);
  k_mgemm<HIDDIM, 3><<<(MROWS/256)*3, 512, 0, stream>>>(
      hid, wf2, fc2_b, nullptr, x2b, (float*)d_out, nullptr, 3);
}